// Round 1
// 2604.042 us; speedup vs baseline: 2.4788x; 2.4788x over previous
//
#include <hip/hip_runtime.h>
#include <hip/hip_bf16.h>

#define NN 512
#define NB 32
#define NPANELS 16
#define BDIM 256
#define PF_BDIM 512
#define LB_BDIM 512

// ---------------- ws layout (float offsets) ----------------
// A    : [0,      262144)   512x512 row-major working copy (becomes junk/V-space)
// V    : [262144, 524288)   16 panels x (512x32 row-major, rows local to k0)
// tau  : [524288, 524800)
// T    : [524800, 541184)   16 x 32x32 (row-major, upper tri, zeros below)
// Q    : [541184, 803328)   512x512 fp32 row-major
// Qbf  : [803328, 934400)   512x512 bf16 (ushort)
// total ~3.74 MB

__device__ inline unsigned short f2bf(float x) {
    unsigned int u = __float_as_uint(x);
    return (unsigned short)((u + 0x7FFFu + ((u >> 16) & 1u)) >> 16);  // RNE
}

__global__ __launch_bounds__(BDIM)
void prep_kernel(const float* __restrict__ W, float* __restrict__ A, float* __restrict__ Q)
{
    int idx = blockIdx.x * BDIM + threadIdx.x;
    if (idx < NN * NN) {
        A[idx] = W[idx] + 1e-8f;
        int r = idx >> 9, c = idx & (NN - 1);
        Q[idx] = (r == c) ? 1.0f : 0.0f;
    }
}

// Factor panel p (cols k0..k0+31, rows k0..511) in LDS; LAPACK slarfg convention.
// 512 threads, 16-way row split. S/T recurrence fused into the per-column dot phase:
// for j<c the dot loop computes v_j . v_c (S entries) for free, and the dlarft
// column update runs in the shadow of the rank-1 update.
__global__ __launch_bounds__(PF_BDIM)
void panel_fact(float* __restrict__ A, float* __restrict__ Vbuf,
                float* __restrict__ tau, float* __restrict__ Tbuf, int p)
{
    const int k0 = p * NB;
    const int L  = NN - k0;               // multiple of 32
    const int LP = L + 1;                 // odd column stride (bank-friendly)
    __shared__ float sP[NB * (NN + 1)];   // 64.1 KB max
    __shared__ float red[PF_BDIM];
    __shared__ float red2[8];
    __shared__ float wbuf[NB];
    __shared__ float sdot[NB];
    __shared__ float sc[2];
    __shared__ float Tt[NB][NB];

    const int t = threadIdx.x;
    const int r = t >> 5;                 // 0..15 row group
    const int j = t & 31;                 // column within panel

    for (int idx = t; idx < L * NB; idx += PF_BDIM) {
        int i = idx >> 5, jj = idx & 31;
        sP[jj * LP + i] = A[(k0 + i) * NN + (k0 + jj)];
    }
    __syncthreads();

    for (int c = 0; c < NB; ++c) {
        // ---- norm^2 of below-diagonal part of column c ----
        {
            float part = 0.f;
            int i = c + 1 + t;
            if (i < L) {
                float x = sP[c * LP + i];
                part = x * x;
            }
            #pragma unroll
            for (int off = 32; off > 0; off >>= 1)
                part += __shfl_down(part, off, 64);
            if ((t & 63) == 0) red2[t >> 6] = part;
        }
        __syncthreads();
        if (t == 0) {
            float xn2 = 0.f;
            #pragma unroll
            for (int g = 0; g < 8; ++g) xn2 += red2[g];
            float alpha = sP[c * LP + c];
            float tc, inv;
            if (xn2 <= 0.f) { tc = 0.f; inv = 0.f; }       // H = I (LAPACK xnorm==0 path)
            else {
                float nrm  = sqrtf(alpha * alpha + xn2);
                float beta = (alpha >= 0.f) ? -nrm : nrm;  // beta = -sign(alpha)*||.||
                tc  = (beta - alpha) / beta;
                inv = 1.f / (alpha - beta);
            }
            sc[0] = tc; sc[1] = inv;
        }
        __syncthreads();
        const float tc = sc[0], inv = sc[1];
        // ---- scale col c into v: unit diag, zeros above (R is never needed) ----
        {
            int i = t;
            if (i < L) {
                float x = sP[c * LP + i];
                sP[c * LP + i] = (i > c) ? x * inv : (i == c ? 1.0f : 0.0f);
            }
        }
        __syncthreads();
        // ---- dots: v_c . col_j for all j != c (full range; v_c zeros above c) ----
        // j > c : raw trailing columns -> w_j.   j < c : finalized v_j -> S[j][c].
        {
            float acc = 0.f;
            if (j != c) {
                #pragma unroll 8
                for (int i = r; i < L; i += 16)
                    acc += sP[c * LP + i] * sP[j * LP + i];
            }
            red[t] = acc;
        }
        __syncthreads();
        if (t < NB) {
            float s = 0.f;
            #pragma unroll
            for (int g = 0; g < 16; ++g) s += red[g * NB + t];
            if (t > c)      wbuf[t] = tc * s;
            else if (t < c) sdot[t] = s;
        }
        __syncthreads();
        // ---- a_j -= v * w_j  (full range: v=0 above c; row c is dead R space) ----
        if (j > c) {
            float wv = wbuf[j];
            #pragma unroll 8
            for (int i = r; i < L; i += 16)
                sP[j * LP + i] -= sP[c * LP + i] * wv;
        }
        // ---- dlarft column c (runs on the r==15 half-wave, overlapped) ----
        if (r == 15) {
            if (j < c) {
                float s = 0.f;
                for (int l = j; l < c; ++l) s += Tt[j][l] * sdot[l];
                Tt[j][c] = -tc * s;
            } else if (j == c) {
                Tt[c][c] = tc;
            }
        }
        __syncthreads();
    }

    // ---- write V (unit-lower, zeros above) ----
    for (int idx = t; idx < L * NB; idx += PF_BDIM) {
        int i = idx >> 5, jj = idx & 31;
        Vbuf[p * (NN * NB) + idx] = sP[jj * LP + i];
    }
    // ---- write T (upper tri, zeros below) ----
    for (int q = t; q < NB * NB; q += PF_BDIM) {
        int a = q >> 5, b = q & 31;
        Tbuf[p * (NB * NB) + q] = (a <= b) ? Tt[a][b] : 0.0f;
    }
}

// C[k0: , colStart:512] = (I - V * Top * V^T) C ; Top = T^T if transT else T.
// One WG per 64 columns; 8 waves split rows; V staged in LDS; padded reductions.
__global__ __launch_bounds__(LB_BDIM)
void larfb_kernel(float* __restrict__ C, const float* __restrict__ Vbuf,
                  const float* __restrict__ Tbuf, int p, int colStart, int transT)
{
    const int k0 = p * NB;
    const int L  = NN - k0;
    const float* Vp = Vbuf + p * (NN * NB);
    const float* Tp = Tbuf + p * (NB * NB);

    __shared__ float sT[NB * NB];                      // 4 KB
    __shared__ __align__(16) float Vs[NN * NB];        // 64 KB (L*NB used)
    __shared__ float red[8][64][NB + 1];               // 67.6 KB, stride-33: conflict-free
    __shared__ float w2s[64][NB + 1];                  // 8.4 KB

    const int t   = threadIdx.x;
    const int w   = t >> 6;            // wave id = row chunk (0..7)
    const int jj  = t & 63;
    const int col = colStart + blockIdx.x * 64 + jj;
    const bool valid = col < NN;

    for (int q = t; q < NB * NB; q += LB_BDIM) sT[q] = Tp[q];
    {
        const int nv4 = (L * NB) >> 2;
        const float4* Vp4 = (const float4*)Vp;
        float4* Vs4 = (float4*)Vs;
        for (int q = t; q < nv4; q += LB_BDIM) Vs4[q] = Vp4[q];
    }
    __syncthreads();

    // pass 1: y_partial[m] = sum_i V[i][m] * C[k0+i][col], rows i = w, w+8, ...
    float y[NB];
    #pragma unroll
    for (int m = 0; m < NB; ++m) y[m] = 0.f;
    if (valid) {
        #pragma unroll 4
        for (int i = w; i < L; i += 8) {
            float cij = C[(long)(k0 + i) * NN + col];
            const float4* vr = (const float4*)(Vs + i * NB);
            #pragma unroll
            for (int q4 = 0; q4 < 8; ++q4) {
                float4 v = vr[q4];
                y[4*q4+0] += v.x * cij;
                y[4*q4+1] += v.y * cij;
                y[4*q4+2] += v.z * cij;
                y[4*q4+3] += v.w * cij;
            }
        }
    }
    #pragma unroll
    for (int m = 0; m < NB; ++m) red[w][jj][m] = y[m];
    __syncthreads();
    // sum 8 row-chunk partials -> red[0][jl][m]
    {
        int jl = t & 63, m0 = (t >> 6) * 4;
        #pragma unroll
        for (int mm = 0; mm < 4; ++mm) {
            int m = m0 + mm;
            float s = red[0][jl][m];
            #pragma unroll
            for (int g = 1; g < 8; ++g) s += red[g][jl][m];
            red[0][jl][m] = s;
        }
    }
    __syncthreads();
    // w2 = Top @ y  per column
    {
        int jl = t & 63, m0 = (t >> 6) * 4;
        #pragma unroll
        for (int mm = 0; mm < 4; ++mm) {
            int m = m0 + mm;
            float s = 0.f;
            #pragma unroll
            for (int l = 0; l < NB; ++l) {
                float tv = transT ? sT[l * NB + m] : sT[m * NB + l];
                s += tv * red[0][jl][l];
            }
            w2s[jl][m] = s;
        }
    }
    __syncthreads();
    // pass 2: C -= V @ w2
    if (valid) {
        float w2[NB];
        #pragma unroll
        for (int m = 0; m < NB; ++m) w2[m] = w2s[jj][m];
        #pragma unroll 4
        for (int i = w; i < L; i += 8) {
            const float4* vr = (const float4*)(Vs + i * NB);
            float upd = 0.f;
            #pragma unroll
            for (int q4 = 0; q4 < 8; ++q4) {
                float4 v = vr[q4];
                upd += v.x * w2[4*q4+0] + v.y * w2[4*q4+1]
                     + v.z * w2[4*q4+2] + v.w * w2[4*q4+3];
            }
            C[(long)(k0 + i) * NN + col] -= upd;
        }
    }
}

__global__ __launch_bounds__(BDIM)
void cast_q(const float* __restrict__ Q, unsigned short* __restrict__ Qbf)
{
    int idx = blockIdx.x * BDIM + threadIdx.x;
    if (idx < NN * NN) Qbf[idx] = f2bf(Q[idx]);
}

// ---------------- GEMM: out(131072x512) = in(131072x512 fp32->bf16) @ Qbf^T ----------------
typedef __bf16 bf16x8 __attribute__((ext_vector_type(8)));
typedef float  f32x4  __attribute__((ext_vector_type(4)));

#define BM 128
#define BN 128
#define BK 32

__global__ __launch_bounds__(BDIM)
void gemm_kernel(const float* __restrict__ Ain, const unsigned short* __restrict__ Bt,
                 float* __restrict__ Cout)
{
    __shared__ unsigned short As[BM * BK];  // 8 KB
    __shared__ unsigned short Bs[BN * BK];  // 8 KB

    const int t   = threadIdx.x;
    // XCD-aware swizzle: give each XCD a contiguous chunk of tile-space so the
    // 4 N-tiles sharing an A row-panel hit the same XCD's L2 (grid=4096, %8==0).
    const int bid = (blockIdx.x >> 3) + (blockIdx.x & 7) * (4096 / 8);
    const int nt  = bid & 3;     // 512/128 = 4 N-tiles, fastest-varying for A-reuse
    const int mt  = bid >> 2;
    const int m0  = mt * BM;
    const int n0  = nt * BN;

    const int lane = t & 63;
    const int wave = t >> 6;
    const int wm = wave >> 1, wn = wave & 1;

    f32x4 acc[4][4];
    #pragma unroll
    for (int a = 0; a < 4; ++a)
        #pragma unroll
        for (int b = 0; b < 4; ++b) acc[a][b] = (f32x4){0.f, 0.f, 0.f, 0.f};

    const int mrow_f = lane & 15;
    const int koff   = (lane >> 4) * 8;

    for (int kk = 0; kk < NN; kk += BK) {
        // stage A tile: 128x32 fp32 -> bf16 (fused convert)
        #pragma unroll
        for (int q = 0; q < 4; ++q) {
            int pidx = t + q * BDIM;           // 0..1023 float4s
            int mrow = pidx >> 3;
            int kq   = pidx & 7;
            const float4 a4 = *(const float4*)(Ain + (long)(m0 + mrow) * NN + kk + kq * 4);
            ushort4 b4;
            b4.x = f2bf(a4.x); b4.y = f2bf(a4.y); b4.z = f2bf(a4.z); b4.w = f2bf(a4.w);
            *(ushort4*)(&As[mrow * BK + kq * 4]) = b4;
        }
        // stage B tile: 128x32 bf16 straight copy
        #pragma unroll
        for (int q = 0; q < 2; ++q) {
            int pidx = t + q * BDIM;           // 0..511 16B chunks
            int nrow = pidx >> 2;
            int k8   = pidx & 3;
            float4 raw = *(const float4*)(Bt + (long)(n0 + nrow) * NN + kk + k8 * 8);
            *(float4*)(&Bs[nrow * BK + k8 * 8]) = raw;
        }
        __syncthreads();

        bf16x8 af[4], bfr[4];
        #pragma unroll
        for (int a = 0; a < 4; ++a)
            af[a] = *(const bf16x8*)(&As[(wm * 64 + a * 16 + mrow_f) * BK + koff]);
        #pragma unroll
        for (int b = 0; b < 4; ++b)
            bfr[b] = *(const bf16x8*)(&Bs[(wn * 64 + b * 16 + mrow_f) * BK + koff]);
        #pragma unroll
        for (int a = 0; a < 4; ++a)
            #pragma unroll
            for (int b = 0; b < 4; ++b)
                acc[a][b] = __builtin_amdgcn_mfma_f32_16x16x32_bf16(af[a], bfr[b], acc[a][b], 0, 0, 0);
        __syncthreads();
    }

    #pragma unroll
    for (int a = 0; a < 4; ++a) {
        int rbase = m0 + wm * 64 + a * 16 + (lane >> 4) * 4;
        #pragma unroll
        for (int b = 0; b < 4; ++b) {
            int cidx = n0 + wn * 64 + b * 16 + (lane & 15);
            #pragma unroll
            for (int r = 0; r < 4; ++r)
                Cout[(long)(rbase + r) * NN + cidx] = acc[a][b][r];
        }
    }
}

extern "C" void kernel_launch(void* const* d_in, const int* in_sizes, int n_in,
                              void* d_out, int out_size, void* d_ws, size_t ws_size,
                              hipStream_t stream)
{
    const float* inp = (const float*)d_in[0];
    const float* wgt = (const float*)d_in[1];
    float* ws  = (float*)d_ws;
    float* A   = ws;
    float* V   = ws + 262144;
    float* tau = ws + 524288;
    float* T   = ws + 524800;
    float* Q   = ws + 541184;
    unsigned short* Qbf = (unsigned short*)(ws + 803328);
    float* out = (float*)d_out;

    prep_kernel<<<(NN * NN + BDIM - 1) / BDIM, BDIM, 0, stream>>>(wgt, A, Q);

    for (int p = 0; p < NPANELS; ++p) {
        panel_fact<<<1, PF_BDIM, 0, stream>>>(A, V, tau, T, p);
        int colStart = p * NB + NB;
        int nc = NN - colStart;
        if (nc > 0)
            larfb_kernel<<<(nc + 63) / 64, LB_BDIM, 0, stream>>>(A, V, T, p, colStart, 1);
    }
    for (int p = NPANELS - 1; p >= 0; --p) {
        int colStart = p * NB;
        int nc = NN - colStart;
        larfb_kernel<<<(nc + 63) / 64, LB_BDIM, 0, stream>>>(Q, V, T, p, colStart, 0);
    }
    cast_q<<<(NN * NN + BDIM - 1) / BDIM, BDIM, 0, stream>>>(Q, Qbf);

    gemm_kernel<<<(131072 / BM) * (NN / BN), BDIM, 0, stream>>>(inp, Qbf, out);
}